// Round 1
// baseline (446.942 us; speedup 1.0000x reference)
//
#include <hip/hip_runtime.h>
#include <hip/hip_fp16.h>
#include <stdint.h>

#define S_LEN 2048
#define BATCH 2
#define NHEAD 16
#define DKH 64
#define DMODEL 1024
#define MTOT (BATCH * S_LEN)  // 4096

typedef _Float16 h16;
typedef __attribute__((ext_vector_type(8))) _Float16 f16x8;
typedef __attribute__((ext_vector_type(4))) _Float16 f16x4;
typedef __attribute__((ext_vector_type(4))) float f32x4;

union H2 { unsigned int u; h16 h[2]; };
union F8 { unsigned int u[4]; f16x8 v; };

__device__ __forceinline__ h16 f2h(float f) { return (h16)f; }

typedef __attribute__((address_space(1))) void GV;
typedef __attribute__((address_space(3))) void LV;
__device__ __forceinline__ void load_lds16(const h16* g, h16* l) {
    __builtin_amdgcn_global_load_lds((GV*)g, (LV*)l, 16, 0, 0);
}

// ---------------- fp32 -> fp16 convert, vectorized ----------------
__global__ void cvt_f32_f16(const float* __restrict__ src, h16* __restrict__ dst, int n) {
    int i = (blockIdx.x * blockDim.x + threadIdx.x) * 4;
    if (i >= n) return;
    const float4 v = *(const float4*)(src + i);
    f16x4 o = { (h16)v.x, (h16)v.y, (h16)v.z, (h16)v.w };
    *(f16x4*)(dst + i) = o;
}

// ---------------- GEMM: C[M,N] = A[M,K] * W[N,K]^T + bias ----------------
// MODE 0: f16 out, layout [B,H,S,64], value scaled by `scale` (Q/K projections)
// MODE 1: f16 out, layout [B,H,64,S]  (V projection, transposed for PV)
// MODE 2: f32 out, row-major [M,N]    (output projection)
template <int MODE>
__global__ __launch_bounds__(256) void gemm_bt(const h16* __restrict__ A,
                                               const h16* __restrict__ W,
                                               const float* __restrict__ bias,
                                               void* __restrict__ out, float scale) {
    constexpr int K = DMODEL;
    const int tid = threadIdx.x;
    const int lane = tid & 63, wid = tid >> 6;
    const int g = lane >> 4, lr = lane & 15;
    const int wr = wid >> 1, wc = wid & 1;
    const int bm = blockIdx.x * 128, bn = blockIdx.y * 128;

    __shared__ h16 lA[128 * 32];
    __shared__ h16 lB[128 * 32];

    const h16* Ap = A + (size_t)(bm + (tid >> 2)) * K + (tid & 3) * 8;
    const h16* Wp = W + (size_t)(bn + (tid >> 2)) * K + (tid & 3) * 8;

    f32x4 acc[4][4] = {};

    for (int k0 = 0; k0 < K; k0 += 32) {
        load_lds16(Ap + k0,          &lA[tid * 8]);
        load_lds16(Ap + 64 * K + k0, &lA[2048 + tid * 8]);
        load_lds16(Wp + k0,          &lB[tid * 8]);
        load_lds16(Wp + 64 * K + k0, &lB[2048 + tid * 8]);
        __syncthreads();
        f16x8 af[4], bf[4];
#pragma unroll
        for (int i = 0; i < 4; ++i) {
            af[i] = *(const f16x8*)&lA[(wr * 64 + i * 16 + lr) * 32 + g * 8];
            bf[i] = *(const f16x8*)&lB[(wc * 64 + i * 16 + lr) * 32 + g * 8];
        }
#pragma unroll
        for (int i = 0; i < 4; ++i)
#pragma unroll
            for (int j = 0; j < 4; ++j)
                acc[i][j] = __builtin_amdgcn_mfma_f32_16x16x32_f16(af[i], bf[j], acc[i][j], 0, 0, 0);
        __syncthreads();
    }

    // Epilogue. Lane holds rows row0..row0+3 (m) at col (n) per fragment.
#pragma unroll
    for (int i = 0; i < 4; ++i) {
        const int row0 = bm + wr * 64 + i * 16 + g * 4;
#pragma unroll
        for (int j = 0; j < 4; ++j) {
            const int col = bn + wc * 64 + j * 16 + lr;
            const float bv = bias[col];
            f32x4 v = acc[i][j];
            if constexpr (MODE == 2) {
                float* o = (float*)out;
#pragma unroll
                for (int r = 0; r < 4; ++r) o[(size_t)(row0 + r) * DMODEL + col] = v[r] + bv;
            } else {
                const int b = row0 >> 11, s0 = row0 & (S_LEN - 1);
                const int h = col >> 6, d = col & 63;
                h16* o = (h16*)out;
                if constexpr (MODE == 0) {
                    size_t base = ((size_t)(b * NHEAD + h) * S_LEN + s0) * DKH + d;
#pragma unroll
                    for (int r = 0; r < 4; ++r)
                        o[base + (size_t)r * DKH] = f2h((v[r] + bv) * scale);
                } else {  // MODE 1: Vt[b][h][d][s], 4 consecutive s -> 8B store
                    size_t base = ((size_t)(b * NHEAD + h) * DKH + d) * S_LEN + s0;
                    f16x4 pk = { f2h(v[0] + bv), f2h(v[1] + bv), f2h(v[2] + bv), f2h(v[3] + bv) };
                    *(f16x4*)&o[base] = pk;
                }
            }
        }
    }
}

// ---------------- Flash attention ----------------
// Q: [B*H, S, 64] (pre-scaled by 1/8), K: [B*H, S, 64], Vt: [B*H, 64, S]
// ctx out: [B, S, 1024] f16.  Block = 4 waves; wave handles 16 q-rows.
__global__ __launch_bounds__(256) void flash_attn(const h16* __restrict__ Q,
                                                  const h16* __restrict__ Kp,
                                                  const h16* __restrict__ Vt,
                                                  h16* __restrict__ ctx) {
    const int tid = threadIdx.x;
    const int lane = tid & 63, wid = tid >> 6;
    const int g = lane >> 4, lr = lane & 15;
    const int bh = blockIdx.y;
    const int qbase = blockIdx.x * 64 + wid * 16;

    const h16* Qh = Q + (size_t)bh * S_LEN * DKH;
    const h16* Kh = Kp + (size_t)bh * S_LEN * DKH;
    const h16* Vh = Vt + (size_t)bh * DKH * S_LEN;

    // Q fragments (B-operand of swapped QK^T): lane provides Q[q=qbase+lr][dk=ks*32+g*8..+8]
    f16x8 qf[2];
    qf[0] = *(const f16x8*)&Qh[(size_t)(qbase + lr) * DKH + g * 8];
    qf[1] = *(const f16x8*)&Qh[(size_t)(qbase + lr) * DKH + 32 + g * 8];

    f32x4 cacc[4] = {};  // ctx^T: d = mf*16 + g*4 + r, q = qbase + lr
    float m_run = -1e30f, l_run = 0.f;

    for (int kv0 = 0; kv0 < S_LEN; kv0 += 64) {
        // S^T[kv][q]: A-operand = K rows, B-operand = Q
        f32x4 sa[4] = {};
#pragma unroll
        for (int ks = 0; ks < 2; ++ks)
#pragma unroll
            for (int mf = 0; mf < 4; ++mf) {
                f16x8 kf = *(const f16x8*)&Kh[(size_t)(kv0 + mf * 16 + lr) * DKH + ks * 32 + g * 8];
                sa[mf] = __builtin_amdgcn_mfma_f32_16x16x32_f16(kf, qf[ks], sa[mf], 0, 0, 0);
            }
        // lane holds s for q = qbase+lr, kv = kv0 + mf*16 + g*4 + r
        float tmax = sa[0][0];
#pragma unroll
        for (int mf = 0; mf < 4; ++mf)
#pragma unroll
            for (int r = 0; r < 4; ++r) tmax = fmaxf(tmax, sa[mf][r]);
        tmax = fmaxf(tmax, __shfl_xor(tmax, 16));
        tmax = fmaxf(tmax, __shfl_xor(tmax, 32));
        const float m_new = fmaxf(m_run, tmax);
        const float alpha = __expf(m_run - m_new);
        float p[4][4];
        float psum = 0.f;
#pragma unroll
        for (int mf = 0; mf < 4; ++mf)
#pragma unroll
            for (int r = 0; r < 4; ++r) {
                p[mf][r] = __expf(sa[mf][r] - m_new);
                psum += p[mf][r];
            }
        psum += __shfl_xor(psum, 16);
        psum += __shfl_xor(psum, 32);
        l_run = l_run * alpha + psum;
        m_run = m_new;
#pragma unroll
        for (int mf = 0; mf < 4; ++mf)
#pragma unroll
            for (int r = 0; r < 4; ++r) cacc[mf][r] *= alpha;

        // pack P to f16 pairs: pk[mf][w]: w=0 -> (r0,r1), w=1 -> (r2,r3)
        unsigned int pk[4][2];
#pragma unroll
        for (int mf = 0; mf < 4; ++mf) {
            H2 a, b2;
            a.h[0] = f2h(p[mf][0]); a.h[1] = f2h(p[mf][1]);
            b2.h[0] = f2h(p[mf][2]); b2.h[1] = f2h(p[mf][3]);
            pk[mf][0] = a.u; pk[mf][1] = b2.u;
        }
        // PV (swapped): ctx^T += Vt * P^T. B-operand (P) lane needs
        // P[q=lr][kv = ks*32 + g*8 + jj]; source lane = lr + 16*((g&1)*2 + (wi>>1)),
        // source frag mf' = ks*2 + (g>>1), word = wi&1.
#pragma unroll
        for (int ks = 0; ks < 2; ++ks) {
            F8 pf;
#pragma unroll
            for (int wi = 0; wi < 4; ++wi) {
                int srcl = lr + 16 * ((g & 1) * 2 + (wi >> 1));
                unsigned int lo = __shfl(pk[2 * ks + 0][wi & 1], srcl);
                unsigned int hi = __shfl(pk[2 * ks + 1][wi & 1], srcl);
                pf.u[wi] = (g >= 2) ? hi : lo;
            }
#pragma unroll
            for (int mf = 0; mf < 4; ++mf) {
                f16x8 vf = *(const f16x8*)&Vh[(size_t)(mf * 16 + lr) * S_LEN + kv0 + ks * 32 + g * 8];
                cacc[mf] = __builtin_amdgcn_mfma_f32_16x16x32_f16(vf, pf.v, cacc[mf], 0, 0, 0);
            }
        }
    }

    const float inv = 1.f / l_run;
    const int b = bh >> 4, h = bh & (NHEAD - 1);
    const int qabs = qbase + lr;
    h16* o = ctx + ((size_t)(b * S_LEN + qabs)) * DMODEL + h * DKH;
#pragma unroll
    for (int mf = 0; mf < 4; ++mf) {
        f16x4 st = { f2h(cacc[mf][0] * inv), f2h(cacc[mf][1] * inv),
                     f2h(cacc[mf][2] * inv), f2h(cacc[mf][3] * inv) };
        *(f16x4*)&o[mf * 16 + g * 4] = st;
    }
}

extern "C" void kernel_launch(void* const* d_in, const int* in_sizes, int n_in,
                              void* d_out, int out_size, void* d_ws, size_t ws_size,
                              hipStream_t stream) {
    const float* q_in = (const float*)d_in[0];
    const float* k_in = (const float*)d_in[1];
    const float* v_in = (const float*)d_in[2];
    const float* w_q = (const float*)d_in[3];
    const float* b_q = (const float*)d_in[4];
    const float* w_k = (const float*)d_in[5];
    const float* b_k = (const float*)d_in[6];
    const float* w_v = (const float*)d_in[7];
    const float* b_v = (const float*)d_in[8];
    const float* w_o = (const float*)d_in[9];
    const float* b_o = (const float*)d_in[10];
    float* out = (float*)d_out;

    char* ws = (char*)d_ws;
    h16* Wq = (h16*)(ws + (0ull << 20));
    h16* Wk = (h16*)(ws + (2ull << 20));
    h16* Wv = (h16*)(ws + (4ull << 20));
    h16* Wo = (h16*)(ws + (6ull << 20));
    h16* Qp = (h16*)(ws + (8ull << 20));
    h16* Kp = (h16*)(ws + (16ull << 20));
    h16* Vt = (h16*)(ws + (24ull << 20));
    h16* Xv = (h16*)(ws + (32ull << 20));  // dead after V projection
    h16* ctx = Xv;                         // reuse for attention output
    h16* Xq = (h16*)d_out;                 // d_out as scratch: 16MB = two 8MB f16 buffers
    h16* Xk = (h16*)((char*)d_out + (8ull << 20));

    const int nAct = MTOT * DMODEL;    // 4,194,304
    const int nW = DMODEL * DMODEL;    // 1,048,576
    cvt_f32_f16<<<nAct / 1024, 256, 0, stream>>>(q_in, Xq, nAct);
    cvt_f32_f16<<<nAct / 1024, 256, 0, stream>>>(k_in, Xk, nAct);
    cvt_f32_f16<<<nAct / 1024, 256, 0, stream>>>(v_in, Xv, nAct);
    cvt_f32_f16<<<nW / 1024, 256, 0, stream>>>(w_q, Wq, nW);
    cvt_f32_f16<<<nW / 1024, 256, 0, stream>>>(w_k, Wk, nW);
    cvt_f32_f16<<<nW / 1024, 256, 0, stream>>>(w_v, Wv, nW);
    cvt_f32_f16<<<nW / 1024, 256, 0, stream>>>(w_o, Wo, nW);

    dim3 gg(MTOT / 128, DMODEL / 128);
    gemm_bt<0><<<gg, 256, 0, stream>>>(Xq, Wq, b_q, Qp, 0.125f);  // 1/sqrt(64) folded into Q
    gemm_bt<0><<<gg, 256, 0, stream>>>(Xk, Wk, b_k, Kp, 1.0f);
    gemm_bt<1><<<gg, 256, 0, stream>>>(Xv, Wv, b_v, Vt, 1.0f);

    dim3 ga(S_LEN / 64, BATCH * NHEAD);
    flash_attn<<<ga, 256, 0, stream>>>(Qp, Kp, Vt, ctx);

    gemm_bt<2><<<gg, 256, 0, stream>>>(ctx, Wo, b_o, out, 1.0f);
}

// Round 2
// 412.126 us; speedup vs baseline: 1.0845x; 1.0845x over previous
//
#include <hip/hip_runtime.h>
#include <hip/hip_fp16.h>
#include <stdint.h>

#define S_LEN 2048
#define BATCH 2
#define NHEAD 16
#define DKH 64
#define DMODEL 1024
#define MTOT (BATCH * S_LEN)  // 4096
#define NT (S_LEN / 64)       // 32 kv tiles

typedef _Float16 h16;
typedef __attribute__((ext_vector_type(8))) _Float16 f16x8;
typedef __attribute__((ext_vector_type(4))) _Float16 f16x4;
typedef __attribute__((ext_vector_type(4))) float f32x4;

union H2 { unsigned int u; h16 h[2]; };
union F8 { unsigned int u[4]; f16x8 v; };

__device__ __forceinline__ h16 f2h(float f) { return (h16)f; }

typedef __attribute__((address_space(1))) void GV;
typedef __attribute__((address_space(3))) void LV;
__device__ __forceinline__ void load_lds16(const h16* g, h16* l) {
    __builtin_amdgcn_global_load_lds((GV*)g, (LV*)l, 16, 0, 0);
}

// ---------------- fp32 -> fp16 converts (merged launches) ----------------
__global__ void cvt_acts(const float* __restrict__ q, const float* __restrict__ k,
                         const float* __restrict__ v, h16* __restrict__ Xq,
                         h16* __restrict__ Xk, h16* __restrict__ Xv) {
    const int r = blockIdx.y;
    const float* s = r == 0 ? q : r == 1 ? k : v;
    h16* d = r == 0 ? Xq : r == 1 ? Xk : Xv;
    const int i = (blockIdx.x * 256 + threadIdx.x) * 4;
    const float4 val = *(const float4*)(s + i);
    f16x4 o = { (h16)val.x, (h16)val.y, (h16)val.z, (h16)val.w };
    *(f16x4*)(d + i) = o;
}

__global__ void cvt_wts(const float* __restrict__ a, const float* __restrict__ b,
                        const float* __restrict__ c, const float* __restrict__ e,
                        h16* __restrict__ A, h16* __restrict__ B,
                        h16* __restrict__ C, h16* __restrict__ E) {
    const int r = blockIdx.y;
    const float* s = r == 0 ? a : r == 1 ? b : r == 2 ? c : e;
    h16* d = r == 0 ? A : r == 1 ? B : r == 2 ? C : E;
    const int i = (blockIdx.x * 256 + threadIdx.x) * 4;
    const float4 val = *(const float4*)(s + i);
    f16x4 o = { (h16)val.x, (h16)val.y, (h16)val.z, (h16)val.w };
    *(f16x4*)(d + i) = o;
}

// ---------------- GEMM core: 128x64 tile, BK=32, 4 waves ----------------
// C[M,N] = A[M,K] * W[N,K]^T + bias
// MODE 0: f16 out, [B,H,S,64], scaled (Q/K proj). MODE 1: f16 out, [B,H,64,S] (V).
// MODE 2: f32 out row-major (O proj).
template <int MODE>
__device__ __forceinline__ void gemm_body(const h16* __restrict__ A,
                                          const h16* __restrict__ W,
                                          const float* __restrict__ bias,
                                          void* __restrict__ out, float scale,
                                          int bm, int bn, h16* lA, h16* lB) {
    constexpr int K = DMODEL;
    const int tid = threadIdx.x;
    const int lane = tid & 63, wid = tid >> 6;
    const int g = lane >> 4, lr = lane & 15;

    const h16* Ap = A + (size_t)(bm + (tid >> 2)) * K + (tid & 3) * 8;
    const h16* Wp = W + (size_t)(bn + (tid >> 2)) * K + (tid & 3) * 8;

    f32x4 acc[2][4] = {};

    for (int k0 = 0; k0 < K; k0 += 32) {
        load_lds16(Ap + k0,          &lA[tid * 8]);
        load_lds16(Ap + 64 * K + k0, &lA[2048 + tid * 8]);
        load_lds16(Wp + k0,          &lB[tid * 8]);
        __syncthreads();
        f16x8 af[2], bf[4];
#pragma unroll
        for (int i = 0; i < 2; ++i)
            af[i] = *(const f16x8*)&lA[(wid * 32 + i * 16 + lr) * 32 + g * 8];
#pragma unroll
        for (int j = 0; j < 4; ++j)
            bf[j] = *(const f16x8*)&lB[(j * 16 + lr) * 32 + g * 8];
#pragma unroll
        for (int i = 0; i < 2; ++i)
#pragma unroll
            for (int j = 0; j < 4; ++j)
                acc[i][j] = __builtin_amdgcn_mfma_f32_16x16x32_f16(af[i], bf[j], acc[i][j], 0, 0, 0);
        __syncthreads();
    }

#pragma unroll
    for (int i = 0; i < 2; ++i) {
        const int row0 = bm + wid * 32 + i * 16 + g * 4;
#pragma unroll
        for (int j = 0; j < 4; ++j) {
            const int col = bn + j * 16 + lr;
            const float bv = bias[col];
            f32x4 v = acc[i][j];
            if constexpr (MODE == 2) {
                float* o = (float*)out;
#pragma unroll
                for (int r = 0; r < 4; ++r) o[(size_t)(row0 + r) * DMODEL + col] = v[r] + bv;
            } else {
                const int b = row0 >> 11, s0 = row0 & (S_LEN - 1);
                const int h = col >> 6, d = col & 63;
                h16* o = (h16*)out;
                if constexpr (MODE == 0) {
                    size_t base = ((size_t)(b * NHEAD + h) * S_LEN + s0) * DKH + d;
#pragma unroll
                    for (int r = 0; r < 4; ++r)
                        o[base + (size_t)r * DKH] = f2h((v[r] + bv) * scale);
                } else {
                    size_t base = ((size_t)(b * NHEAD + h) * DKH + d) * S_LEN + s0;
                    f16x4 pk = { f2h(v[0] + bv), f2h(v[1] + bv), f2h(v[2] + bv), f2h(v[3] + bv) };
                    *(f16x4*)&o[base] = pk;
                }
            }
        }
    }
}

// Fused Q/K/V projections: blockIdx.z selects tensor (block-uniform branch).
__global__ __launch_bounds__(256) void gemm_qkv(
        const h16* __restrict__ Xq, const h16* __restrict__ Xk, const h16* __restrict__ Xv,
        const h16* __restrict__ Wq, const h16* __restrict__ Wk, const h16* __restrict__ Wv,
        const float* __restrict__ bq, const float* __restrict__ bk, const float* __restrict__ bv,
        h16* __restrict__ Qp, h16* __restrict__ Kp, h16* __restrict__ Vt) {
    __shared__ h16 lA[128 * 32];
    __shared__ h16 lB[64 * 32];
    const int bm = blockIdx.x * 128, bn = blockIdx.y * 64;
    const int which = blockIdx.z;
    if (which == 0)
        gemm_body<0>(Xq, Wq, bq, Qp, 0.125f, bm, bn, lA, lB);
    else if (which == 1)
        gemm_body<0>(Xk, Wk, bk, Kp, 1.0f, bm, bn, lA, lB);
    else
        gemm_body<1>(Xv, Wv, bv, Vt, 1.0f, bm, bn, lA, lB);
}

__global__ __launch_bounds__(256) void gemm_o(const h16* __restrict__ A,
                                              const h16* __restrict__ W,
                                              const float* __restrict__ bias,
                                              float* __restrict__ out) {
    __shared__ h16 lA[128 * 32];
    __shared__ h16 lB[64 * 32];
    gemm_body<2>(A, W, bias, out, 1.0f, blockIdx.x * 128, blockIdx.y * 64, lA, lB);
}

// ---------------- Flash attention, software-pipelined ----------------
// Q: [B*H, S, 64] (pre-scaled), K: [B*H, S, 64], Vt: [B*H, 64, S]
// ctx out: [B, S, 1024] f16.  Block = 4 waves; wave handles 16 q-rows.
// Grid: 1024 linear blocks, XCD-swizzled so each XCD owns 4 heads (K+V = 2MB, L2-fit).
__global__ __launch_bounds__(256) void flash_attn(const h16* __restrict__ Q,
                                                  const h16* __restrict__ Kp,
                                                  const h16* __restrict__ Vt,
                                                  h16* __restrict__ ctx) {
    const int tid = threadIdx.x;
    const int lane = tid & 63, wid = tid >> 6;
    const int g = lane >> 4, lr = lane & 15;
    const int wg = blockIdx.x;                       // 1024 blocks
    const int swz = (wg & 7) * 128 + (wg >> 3);      // chunk per XCD
    const int bh = swz >> 5;                         // 32 q-tiles per head
    const int qbase = (swz & 31) * 64 + wid * 16;

    const h16* Qh = Q + (size_t)bh * S_LEN * DKH;
    const h16* Kh = Kp + (size_t)bh * S_LEN * DKH;
    const h16* Vh = Vt + (size_t)bh * DKH * S_LEN;

    f16x8 qf[2];
    qf[0] = *(const f16x8*)&Qh[(size_t)(qbase + lr) * DKH + g * 8];
    qf[1] = *(const f16x8*)&Qh[(size_t)(qbase + lr) * DKH + 32 + g * 8];

    // lane-fixed base pointers: K row lr (+mf*16 +kv), col g*8 (+ks*32)
    const h16* kptr = &Kh[(size_t)lr * DKH + g * 8];
    const h16* vptr = &Vh[(size_t)lr * S_LEN + g * 8];

    f16x8 kreg[8], vreg[8];
#pragma unroll
    for (int ks = 0; ks < 2; ++ks)
#pragma unroll
        for (int mf = 0; mf < 4; ++mf)
            kreg[ks * 4 + mf] = *(const f16x8*)&kptr[(size_t)(mf * 16) * DKH + ks * 32];

    f32x4 cacc[4] = {};  // ctx^T: d = mf*16 + g*4 + r, q = qbase + lr
    float m_run = -1e30f, l_run = 0.f;

    for (int t = 0; t < NT; ++t) {
        const int kv0 = t * 64;
        // V loads for this tile — consumed after softmax (latency covered)
#pragma unroll
        for (int ks = 0; ks < 2; ++ks)
#pragma unroll
            for (int mf = 0; mf < 4; ++mf)
                vreg[ks * 4 + mf] = *(const f16x8*)&vptr[(size_t)(mf * 16) * S_LEN + kv0 + ks * 32];

        // QK^T (swapped): S^T[kv][q] = K * Q^T
        f32x4 sa[4] = {};
#pragma unroll
        for (int ks = 0; ks < 2; ++ks)
#pragma unroll
            for (int mf = 0; mf < 4; ++mf)
                sa[mf] = __builtin_amdgcn_mfma_f32_16x16x32_f16(kreg[ks * 4 + mf], qf[ks], sa[mf], 0, 0, 0);

        // prefetch K for t+1 (wraps to tile 0 at end — harmless)
        const int kvn = (t + 1 < NT) ? (kv0 + 64) : 0;
#pragma unroll
        for (int ks = 0; ks < 2; ++ks)
#pragma unroll
            for (int mf = 0; mf < 4; ++mf)
                kreg[ks * 4 + mf] = *(const f16x8*)&kptr[(size_t)(kvn + mf * 16) * DKH + ks * 32];

        // ---- softmax (lane holds q=qbase+lr; kv = kv0 + mf*16 + g*4 + r) ----
        float mxm[4];
#pragma unroll
        for (int mf = 0; mf < 4; ++mf)
            mxm[mf] = fmaxf(fmaxf(sa[mf][0], sa[mf][1]), fmaxf(sa[mf][2], sa[mf][3]));
        float tmax = fmaxf(fmaxf(mxm[0], mxm[1]), fmaxf(mxm[2], mxm[3]));
        tmax = fmaxf(tmax, __shfl_xor(tmax, 16));
        tmax = fmaxf(tmax, __shfl_xor(tmax, 32));
        const float m_new = fmaxf(m_run, tmax);
        const float alpha = __expf(m_run - m_new);
#pragma unroll
        for (int mf = 0; mf < 4; ++mf)
#pragma unroll
            for (int r = 0; r < 4; ++r)
                sa[mf][r] = __expf(sa[mf][r] - m_new);
        float sm[4];
#pragma unroll
        for (int mf = 0; mf < 4; ++mf)
            sm[mf] = (sa[mf][0] + sa[mf][1]) + (sa[mf][2] + sa[mf][3]);
        float psum = (sm[0] + sm[1]) + (sm[2] + sm[3]);
        psum += __shfl_xor(psum, 16);
        psum += __shfl_xor(psum, 32);
        l_run = l_run * alpha + psum;
        m_run = m_new;
#pragma unroll
        for (int mf = 0; mf < 4; ++mf)
#pragma unroll
            for (int r = 0; r < 4; ++r) cacc[mf][r] *= alpha;

        // pack P to f16 pairs
        unsigned int pk[4][2];
#pragma unroll
        for (int mf = 0; mf < 4; ++mf) {
            H2 a, b2;
            a.h[0] = f2h(sa[mf][0]); a.h[1] = f2h(sa[mf][1]);
            b2.h[0] = f2h(sa[mf][2]); b2.h[1] = f2h(sa[mf][3]);
            pk[mf][0] = a.u; pk[mf][1] = b2.u;
        }
        // PV (swapped): ctx^T += Vt * P^T; B-operand lane needs P[q=lr][kv=ks*32+g*8+jj]
#pragma unroll
        for (int ks = 0; ks < 2; ++ks) {
            F8 pf;
#pragma unroll
            for (int wi = 0; wi < 4; ++wi) {
                int srcl = lr + 16 * ((g & 1) * 2 + (wi >> 1));
                unsigned int lo = __shfl(pk[2 * ks + 0][wi & 1], srcl);
                unsigned int hi = __shfl(pk[2 * ks + 1][wi & 1], srcl);
                pf.u[wi] = (g >= 2) ? hi : lo;
            }
#pragma unroll
            for (int mf = 0; mf < 4; ++mf)
                cacc[mf] = __builtin_amdgcn_mfma_f32_16x16x32_f16(vreg[ks * 4 + mf], pf.v, cacc[mf], 0, 0, 0);
        }
    }

    const float inv = 1.f / l_run;
    const int b = bh >> 4, h = bh & (NHEAD - 1);
    const int qabs = qbase + lr;
    h16* o = ctx + ((size_t)(b * S_LEN + qabs)) * DMODEL + h * DKH;
#pragma unroll
    for (int mf = 0; mf < 4; ++mf) {
        f16x4 st = { f2h(cacc[mf][0] * inv), f2h(cacc[mf][1] * inv),
                     f2h(cacc[mf][2] * inv), f2h(cacc[mf][3] * inv) };
        *(f16x4*)&o[mf * 16 + g * 4] = st;
    }
}

extern "C" void kernel_launch(void* const* d_in, const int* in_sizes, int n_in,
                              void* d_out, int out_size, void* d_ws, size_t ws_size,
                              hipStream_t stream) {
    const float* q_in = (const float*)d_in[0];
    const float* k_in = (const float*)d_in[1];
    const float* v_in = (const float*)d_in[2];
    const float* w_q = (const float*)d_in[3];
    const float* b_q = (const float*)d_in[4];
    const float* w_k = (const float*)d_in[5];
    const float* b_k = (const float*)d_in[6];
    const float* w_v = (const float*)d_in[7];
    const float* b_v = (const float*)d_in[8];
    const float* w_o = (const float*)d_in[9];
    const float* b_o = (const float*)d_in[10];
    float* out = (float*)d_out;

    char* ws = (char*)d_ws;
    h16* Wq = (h16*)(ws + (0ull << 20));
    h16* Wk = (h16*)(ws + (2ull << 20));
    h16* Wv = (h16*)(ws + (4ull << 20));
    h16* Wo = (h16*)(ws + (6ull << 20));
    h16* Qp = (h16*)(ws + (8ull << 20));
    h16* Kp = (h16*)(ws + (16ull << 20));
    h16* Vt = (h16*)(ws + (24ull << 20));
    h16* Xv = (h16*)(ws + (32ull << 20));  // dead after V projection
    h16* ctx = Xv;                         // reuse for attention output
    h16* Xq = (h16*)d_out;                 // d_out as scratch until final GEMM
    h16* Xk = (h16*)((char*)d_out + (8ull << 20));

    cvt_acts<<<dim3(MTOT * DMODEL / 1024, 3), 256, 0, stream>>>(q_in, k_in, v_in, Xq, Xk, Xv);
    cvt_wts<<<dim3(DMODEL * DMODEL / 1024, 4), 256, 0, stream>>>(w_q, w_k, w_v, w_o, Wq, Wk, Wv, Wo);

    gemm_qkv<<<dim3(MTOT / 128, DMODEL / 64, 3), 256, 0, stream>>>(
        Xq, Xk, Xv, Wq, Wk, Wv, b_q, b_k, b_v, Qp, Kp, Vt);

    flash_attn<<<dim3(1024), 256, 0, stream>>>(Qp, Kp, Vt, ctx);

    gemm_o<<<dim3(MTOT / 128, DMODEL / 64), 256, 0, stream>>>(ctx, Wo, b_o, out);
}